// Round 1
// 462.896 us; speedup vs baseline: 1.0191x; 1.0191x over previous
//
#include <hip/hip_runtime.h>
#include <cstdint>
#include <cstddef>

// ---------------- problem constants ----------------
constexpr int NNODES = 50000;
constexpr int NEDGES = 500000;
constexpr int NRELS  = 8;
constexpr int DIM    = 128;
constexpr int ADIM   = 64;
constexpr int TWOD   = 256;
constexpr int EPB    = 64;
constexpr float SLOPE = 0.01f;

constexpr int XPITCH = TWOD + 8;
constexpr int SPAD = NEDGES + 1024;

typedef __attribute__((ext_vector_type(8))) short short8;
typedef __attribute__((ext_vector_type(4))) float floatx4;

__device__ __forceinline__ unsigned short f2bf(float f) {
    unsigned u = __float_as_uint(f);
    unsigned r = u + 0x7FFFu + ((u >> 16) & 1u);
    return (unsigned short)(r >> 16);
}
__device__ __forceinline__ float bf2f(unsigned short b) {
    return __uint_as_float(((unsigned)b) << 16);
}
// v_rcp_f32-based sigmoid: avoids the ~10-instr correctly-rounded div sequence.
// rel err ~2^-22 << bf16's 2^-8 storage precision.
__device__ __forceinline__ float sigmoid_fast(float x) {
    return __builtin_amdgcn_rcpf(1.0f + __expf(-x));
}

// ---------------- init ----------------
__global__ void k_init(uint2* __restrict__ sMeta, int* __restrict__ histD,
                       int* __restrict__ cursorD, int* __restrict__ cnts) {
    int i = blockIdx.x * blockDim.x + threadIdx.x;
    int stride = gridDim.x * blockDim.x;
    for (int idx = i; idx < SPAD; idx += stride) sMeta[idx] = make_uint2(0xFFFFFFFFu, 0u);
    for (int idx = i; idx < NNODES; idx += stride) { histD[idx] = 0; cursorD[idx] = 0; }
    if (i < 16) cnts[i] = 0;
}

// ---------------- prep: relT transpose via LDS tile; Wl/Wa16 linear ----------------
__global__ __launch_bounds__(256) void k_prep(const float* __restrict__ rel,
                                              const float* __restrict__ W_lin,
                                              const float* __restrict__ W_a,
                                              unsigned short* __restrict__ relT,
                                              unsigned short* __restrict__ Wl,
                                              unsigned short* __restrict__ Wa16) {
    __shared__ float ls[64][65];
    int b = blockIdx.x, t = threadIdx.x;
    if (b < 64) {
        int r = b >> 3, tile = b & 7;
        int d0 = (tile >> 1) * 64, o0 = (tile & 1) * 64;
        const float* rp = rel + ((size_t)r * TWOD + d0) * DIM + o0;
#pragma unroll
        for (int u = 0; u < 16; u++) {
            int v = u * 256 + t;
            int j = v & 63, i = v >> 6;
            ls[i][j] = rp[(size_t)i * DIM + j];
        }
        __syncthreads();
        unsigned short* wp = relT + ((size_t)r * DIM + o0) * TWOD + d0;
#pragma unroll
        for (int u = 0; u < 16; u++) {
            int v = u * 256 + t;
            int ii = v & 63, jj = v >> 6;
            wp[(size_t)jj * TWOD + ii] = f2bf(ls[ii][jj]);
        }
    } else {
        int idx = (b - 64) * 256 + t;
        if (idx < DIM * TWOD) {
            Wl[idx] = f2bf(W_lin[idx]);
        } else {
            int j = idx - DIM * TWOD;
            if (j < ADIM * TWOD) Wa16[j] = f2bf(W_a[j]);
        }
    }
}

// ---------------- h -> bf16 ----------------
__global__ void k_h16(const float* __restrict__ h, unsigned short* __restrict__ h16) {
    int i = blockIdx.x * 256 + threadIdx.x;
    if (i < NNODES * DIM / 8) {
        const float4* hp = (const float4*)(h + (size_t)i * 8);
        float4 a = hp[0], b = hp[1];
        union { unsigned short us[8]; short8 s8; } pk;
        pk.us[0] = f2bf(a.x); pk.us[1] = f2bf(a.y); pk.us[2] = f2bf(a.z); pk.us[3] = f2bf(a.w);
        pk.us[4] = f2bf(b.x); pk.us[5] = f2bf(b.y); pk.us[6] = f2bf(b.z); pk.us[7] = f2bf(b.w);
        *(short8*)&h16[(size_t)i * 8] = pk.s8;
    }
}

// ---------------- fused histogram ----------------
__global__ void k_hist2(const int* __restrict__ ety, const int* __restrict__ dst,
                        int* __restrict__ cnt, int* __restrict__ histD) {
    __shared__ int hist[NRELS];
    int t = threadIdx.x;
    if (t < NRELS) hist[t] = 0;
    __syncthreads();
    int e = blockIdx.x * 256 + t;
    if (e < NEDGES) {
        atomicAdd(&hist[ety[e]], 1);
        atomicAdd(&histD[dst[e]], 1);
    }
    __syncthreads();
    if (t < NRELS && hist[t] > 0) atomicAdd(&cnt[t], hist[t]);
}

// ---------------- scan ----------------
__global__ __launch_bounds__(1024) void k_scan(const int* __restrict__ histD,
                                               int* __restrict__ row_ptr,
                                               const int* __restrict__ cnt,
                                               int* __restrict__ offs) {
    __shared__ int ls[1024];
    const int t = threadIdx.x;
    const int CH = (NNODES + 1023) / 1024;
    const int base = t * CH;
    int s = 0;
    for (int j = 0; j < CH; j++) { int i = base + j; if (i < NNODES) s += histD[i]; }
    ls[t] = s;
    __syncthreads();
    for (int off = 1; off < 1024; off <<= 1) {
        int v = (t >= off) ? ls[t - off] : 0;
        __syncthreads();
        ls[t] += v;
        __syncthreads();
    }
    int run = (t == 0) ? 0 : ls[t - 1];
    for (int j = 0; j < CH; j++) {
        int i = base + j;
        if (i < NNODES) { row_ptr[i] = run; run += histD[i]; }
    }
    if (t == 1023) row_ptr[NNODES] = ls[1023];
    if (t == 0) {
        int off = 0;
        for (int r = 0; r < NRELS; r++) {
            offs[r] = off;
            off += ((cnt[r] + EPB - 1) / EPB) * EPB;
        }
    }
}

// ---------------- single-pass scatter: dst-CSR position + etype bucket slot ----------------
// sMeta[s] = (src | dst<<16, pos); pos = slot in dst-CSR (msgbuf/scoreP index).
__global__ void k_escatter(const int* __restrict__ ety, const int* __restrict__ src,
                           const int* __restrict__ dst, const int* __restrict__ row_ptr,
                           const int* __restrict__ offs,
                           int* __restrict__ cursorD, int* __restrict__ cursorE,
                           uint2* __restrict__ sMeta) {
    __shared__ int hist[NRELS];
    __shared__ int basew[NRELS];
    int t = threadIdx.x;
    if (t < NRELS) hist[t] = 0;
    __syncthreads();
    int e = blockIdx.x * 256 + t;
    int r = -1, rank = 0, sn = 0, dn = 0;
    if (e < NEDGES) {
        r = ety[e]; sn = src[e]; dn = dst[e];
        rank = atomicAdd(&hist[r], 1);
    }
    __syncthreads();
    if (t < NRELS && hist[t] > 0) basew[t] = atomicAdd(&cursorE[t], hist[t]);
    __syncthreads();
    if (e < NEDGES) {
        int s = offs[r] + basew[r] + rank;
        int pos = row_ptr[dn] + atomicAdd(&cursorD[dn], 1);
        sMeta[s] = make_uint2((unsigned)sn | ((unsigned)dn << 16), (unsigned)pos);
    }
}

// ---------------- gates + messages + scores: single merged MFMA K-loop ----------------
__global__ __launch_bounds__(256, 4) void k_gate_msg(
    const unsigned short* __restrict__ h16, const unsigned short* __restrict__ relT,
    const unsigned short* __restrict__ Wa16,
    const uint2* __restrict__ sMeta, const float* __restrict__ b_a,
    const float* __restrict__ ratt, const int* __restrict__ offs,
    unsigned short* __restrict__ msgbuf, float* __restrict__ scoreP) {
    __shared__ unsigned short Xs[EPB * XPITCH];   // 33792 B
    __shared__ int srcn_s[EPB];
    __shared__ int dstn_s[EPB];
    __shared__ int pos_s[EPB];
    __shared__ int val_s[EPB];
    __shared__ float scoreW[EPB][4];

    const int t = threadIdx.x;
    const int base = blockIdx.x * EPB;

    if (t < EPB) {
        uint2 m2 = sMeta[base + t];
        int valid = (m2.x != 0xFFFFFFFFu);
        val_s[t] = valid;
        srcn_s[t] = valid ? (int)(m2.x & 0xFFFFu) : 0;
        dstn_s[t] = valid ? (int)(m2.x >> 16) : 0;
        pos_s[t] = valid ? (int)m2.y : 0;
    }
    __syncthreads();
    if (!val_s[0]) return;

    int r = 0;
#pragma unroll
    for (int i = 1; i < NRELS; i++) if (base >= offs[i]) r = i;

#pragma unroll
    for (int u = 0; u < 8; u++) {
        int v = u * 256 + t;
        int i = v >> 5;
        int c = v & 31;
        int node = (c < 16) ? dstn_s[i] : srcn_s[i];
        *(short8*)&Xs[i * XPITCH + c * 8] = *(const short8*)&h16[(size_t)node * DIM + (c & 15) * 8];
    }

    const int wave = t >> 6;
    const int lane = t & 63;
    const int q = lane >> 4;
    const int l16 = lane & 15;
    const int o16 = wave * 16 + l16;

    const unsigned short* bp0 = relT + ((size_t)r * DIM + (wave * 2 + 0) * 16 + l16) * TWOD + q * 8;
    const unsigned short* bp1 = relT + ((size_t)r * DIM + (wave * 2 + 1) * 16 + l16) * TWOD + q * 8;
    const unsigned short* wb  = Wa16 + (size_t)o16 * TWOD + q * 8;

    // Prefetch the first 4 K-groups of B-fragments BEFORE the barrier so the
    // L2 reads overlap the Xs gather drain (the compiler cannot hoist global
    // loads across __syncthreads). 12 x short8 = 48 VGPR, capped by
    // __launch_bounds__(256,4) -> <=128 VGPR, 4 blocks/CU preserved.
    short8 B0p[4], B1p[4], BSp[4];
#pragma unroll
    for (int ks = 0; ks < 4; ks++) {
        B0p[ks] = *(const short8*)(bp0 + ks * 32);
        B1p[ks] = *(const short8*)(bp1 + ks * 32);
        BSp[ks] = *(const short8*)(wb + ks * 32);
    }

    __syncthreads();

    floatx4 acc[4][2];
    floatx4 accS[4];
#pragma unroll
    for (int m = 0; m < 4; m++) {
        acc[m][0] = (floatx4)(0.0f);
        acc[m][1] = (floatx4)(0.0f);
        accS[m] = (floatx4)(0.0f);
    }

#pragma unroll
    for (int ks = 0; ks < 8; ks++) {
        short8 B0 = (ks < 4) ? B0p[ks & 3] : *(const short8*)(bp0 + ks * 32);
        short8 B1 = (ks < 4) ? B1p[ks & 3] : *(const short8*)(bp1 + ks * 32);
        short8 BS = (ks < 4) ? BSp[ks & 3] : *(const short8*)(wb + ks * 32);
        short8 Af[4];
        const unsigned short* xb = &Xs[l16 * XPITCH + ks * 32 + q * 8];
#pragma unroll
        for (int m = 0; m < 4; m++) Af[m] = *(const short8*)(xb + m * 16 * XPITCH);
#pragma unroll
        for (int m = 0; m < 4; m++) {
            acc[m][0] = __builtin_amdgcn_mfma_f32_16x16x32_bf16(Af[m], B0, acc[m][0], 0, 0, 0);
            acc[m][1] = __builtin_amdgcn_mfma_f32_16x16x32_bf16(Af[m], B1, acc[m][1], 0, 0, 0);
            accS[m]   = __builtin_amdgcn_mfma_f32_16x16x32_bf16(Af[m], BS, accS[m], 0, 0, 0);
        }
    }

    __syncthreads();  // all Xs reads done before overwriting dst half

    // score epilogue
    {
        float ba = b_a[o16];
        float ra = ratt[o16];
#pragma unroll
        for (int m = 0; m < 4; m++) {
#pragma unroll
            for (int rg = 0; rg < 4; rg++) {
                float v = accS[m][rg] + ba;
                v = v > 0.0f ? v : SLOPE * v;
                v *= ra;
#pragma unroll
                for (int off = 8; off > 0; off >>= 1) v += __shfl_xor(v, off, 16);
                if (l16 == 0) scoreW[m * 16 + q * 4 + rg][wave] = v;
            }
        }
    }

    // gate epilogue: msg = sigmoid(acc) * src_h -> Xs dst half (bf16)
#pragma unroll
    for (int m = 0; m < 4; m++) {
        int ib = m * 16 + q * 4;
#pragma unroll
        for (int nn = 0; nn < 2; nn++) {
            int o = (wave * 2 + nn) * 16 + l16;
#pragma unroll
            for (int rg = 0; rg < 4; rg++) {
                int i = ib + rg;
                float g = sigmoid_fast(acc[m][nn][rg]);
                float sh = bf2f(Xs[i * XPITCH + DIM + o]);
                Xs[i * XPITCH + o] = f2bf(sh * g);
            }
        }
    }
    __syncthreads();

#pragma unroll
    for (int u = 0; u < 4; u++) {
        int v = u * 256 + t;
        int i = v >> 4;
        int c = v & 15;
        if (!val_s[i]) continue;
        short8 val = *(const short8*)&Xs[i * XPITCH + c * 8];
        *(short8*)&msgbuf[(size_t)pos_s[i] * DIM + c * 8] = val;
    }
    if (t < EPB && val_s[t]) {
        scoreP[pos_s[t]] = scoreW[t][0] + scoreW[t][1] + scoreW[t][2] + scoreW[t][3];
    }
}

// ---------------- fused softmax + weighted segment-sum -> hN bf16 ----------------
// One wave per node: lane-parallel max/sum reductions, then col-parallel weighted stream.
__global__ __launch_bounds__(256) void k_aggr(const unsigned short* __restrict__ msgbuf,
                                              const float* __restrict__ scoreP,
                                              const int* __restrict__ row_ptr,
                                              unsigned short* __restrict__ hN16) {
    int n = blockIdx.x * 4 + (threadIdx.x >> 6);
    int lane = threadIdx.x & 63;
    if (n >= NNODES) return;
    int p0 = row_ptr[n], p1 = row_ptr[n + 1];
    float a0 = 0.0f, a1 = 0.0f;
    if (p0 < p1) {
        float mx = -3.0e38f;
        for (int p = p0 + lane; p < p1; p += 64) mx = fmaxf(mx, scoreP[p]);
#pragma unroll
        for (int off = 32; off > 0; off >>= 1) mx = fmaxf(mx, __shfl_xor(mx, off));
        float sum = 0.0f;
        for (int p = p0 + lane; p < p1; p += 64) sum += __expf(scoreP[p] - mx);
#pragma unroll
        for (int off = 32; off > 0; off >>= 1) sum += __shfl_xor(sum, off);
        float inv = __builtin_amdgcn_rcpf(sum);
        for (int p = p0; p < p1; p++) {
            float w = __expf(scoreP[p] - mx) * inv;   // broadcast load + cheap exp
            unsigned v = *(const unsigned*)&msgbuf[(size_t)p * DIM + lane * 2];
            a0 += w * bf2f((unsigned short)(v & 0xFFFFu));
            a1 += w * bf2f((unsigned short)(v >> 16));
        }
    }
    unsigned o = (unsigned)f2bf(a0) | ((unsigned)f2bf(a1) << 16);
    *(unsigned*)&hN16[(size_t)n * DIM + lane * 2] = o;
}

// ---------------- out = leaky(W_lin @ [h ; h_N] + b) via MFMA ----------------
__global__ __launch_bounds__(256) void k_out(const unsigned short* __restrict__ h16,
                                             const unsigned short* __restrict__ hN16,
                                             const unsigned short* __restrict__ Wl,
                                             const float* __restrict__ b_lin,
                                             float* __restrict__ out) {
    __shared__ unsigned short Xs[EPB * XPITCH];
    const int t = threadIdx.x;
    const int nb = blockIdx.x * 64;

#pragma unroll
    for (int u = 0; u < 8; u++) {
        int v = u * 256 + t;
        int i = v >> 5;
        int c = v & 31;
        int n = nb + i;
        if (n >= NNODES) n = NNODES - 1;
        const unsigned short* srcp = (c < 16) ? h16 : hN16;
        *(short8*)&Xs[i * XPITCH + c * 8] = *(const short8*)&srcp[(size_t)n * DIM + (c & 15) * 8];
    }

    const int wave = t >> 6;
    const int lane = t & 63;
    const int q = lane >> 4;
    const int l16 = lane & 15;

    short8 Bf[2][8];
#pragma unroll
    for (int nn = 0; nn < 2; nn++) {
        int o = (wave * 2 + nn) * 16 + l16;
        const unsigned short* bp = Wl + (size_t)o * TWOD + q * 8;
#pragma unroll
        for (int ks = 0; ks < 8; ks++) Bf[nn][ks] = *(const short8*)(bp + ks * 32);
    }

    __syncthreads();

    floatx4 acc[4][2];
#pragma unroll
    for (int m = 0; m < 4; m++)
#pragma unroll
        for (int nn = 0; nn < 2; nn++) acc[m][nn] = (floatx4)(0.0f);

#pragma unroll
    for (int ks = 0; ks < 8; ks++) {
        short8 Af[4];
        const unsigned short* xb = &Xs[l16 * XPITCH + ks * 32 + q * 8];
#pragma unroll
        for (int m = 0; m < 4; m++) Af[m] = *(const short8*)(xb + m * 16 * XPITCH);
#pragma unroll
        for (int m = 0; m < 4; m++)
#pragma unroll
            for (int nn = 0; nn < 2; nn++)
                acc[m][nn] = __builtin_amdgcn_mfma_f32_16x16x32_bf16(Af[m], Bf[nn][ks], acc[m][nn], 0, 0, 0);
    }

#pragma unroll
    for (int m = 0; m < 4; m++) {
        int ib = m * 16 + q * 4;
#pragma unroll
        for (int nn = 0; nn < 2; nn++) {
            int o = (wave * 2 + nn) * 16 + l16;
            float bl = b_lin[o];
#pragma unroll
            for (int rg = 0; rg < 4; rg++) {
                int n = nb + ib + rg;
                if (n < NNODES) {
                    float val = acc[m][nn][rg] + bl;
                    val = val > 0.0f ? val : SLOPE * val;
                    out[(size_t)n * DIM + o] = val;
                }
            }
        }
    }
}

// ---------------- launcher ----------------
extern "C" void kernel_launch(void* const* d_in, const int* in_sizes, int n_in,
                              void* d_out, int out_size, void* d_ws, size_t ws_size,
                              hipStream_t stream) {
    const float* h     = (const float*)d_in[0];
    const float* rel   = (const float*)d_in[1];
    const float* ratt  = (const float*)d_in[2];
    const float* W_a   = (const float*)d_in[3];
    const float* b_a   = (const float*)d_in[4];
    const float* W_lin = (const float*)d_in[5];
    const float* b_lin = (const float*)d_in[6];
    const int* src = (const int*)d_in[7];
    const int* dst = (const int*)d_in[8];
    const int* ety = (const int*)d_in[9];
    float* out = (float*)d_out;

    // workspace layout (~161 MB)
    float* scoreP = (float*)d_ws;                                   // E
    unsigned short* h16  = (unsigned short*)(scoreP + NEDGES);      // N*128 bf16
    unsigned short* hN16 = h16 + (size_t)NNODES * DIM;              // N*128 bf16
    unsigned short* relT = hN16 + (size_t)NNODES * DIM;             // 8*128*256 bf16
    unsigned short* Wl   = relT + (size_t)NRELS * DIM * TWOD;       // 128*256 bf16
    unsigned short* Wa16 = Wl + (size_t)DIM * TWOD;                 // 64*256 bf16
    uint2* sMeta = (uint2*)(Wa16 + (size_t)ADIM * TWOD);            // SPAD uint2
    int* row_ptr = (int*)(sMeta + SPAD);                            // N+1
    int* histD   = row_ptr + (NNODES + 1);                          // N
    int* cursorD = histD + NNODES;                                  // N
    int* cnts    = cursorD + NNODES;                                // 16
    int* offs    = cnts + 16;                                       // 8
    unsigned short* msgbuf = (unsigned short*)(((uintptr_t)(offs + 8) + 255) & ~(uintptr_t)255); // E*128 bf16

    k_init<<<2048, 256, 0, stream>>>(sMeta, histD, cursorD, cnts);
    k_prep<<<64 + (DIM * TWOD + ADIM * TWOD + 255) / 256, 256, 0, stream>>>(
        rel, W_lin, W_a, relT, Wl, Wa16);
    k_h16<<<(NNODES * DIM / 8 + 255) / 256, 256, 0, stream>>>(h, h16);
    k_hist2<<<(NEDGES + 255) / 256, 256, 0, stream>>>(ety, dst, cnts, histD);
    k_scan<<<1, 1024, 0, stream>>>(histD, row_ptr, cnts, offs);
    k_escatter<<<(NEDGES + 255) / 256, 256, 0, stream>>>(
        ety, src, dst, row_ptr, offs, cursorD, cnts + 8, sMeta);
    k_gate_msg<<<(NEDGES + 8 * EPB + EPB - 1) / EPB, 256, 0, stream>>>(
        h16, relT, Wa16, sMeta, b_a, ratt, offs, msgbuf, scoreP);
    k_aggr<<<(NNODES + 3) / 4, 256, 0, stream>>>(msgbuf, scoreP, row_ptr, hN16);
    k_out<<<(NNODES + 63) / 64, 256, 0, stream>>>(h16, hN16, Wl, b_lin, out);
}

// Round 2
// 459.117 us; speedup vs baseline: 1.0275x; 1.0082x over previous
//
#include <hip/hip_runtime.h>
#include <cstdint>
#include <cstddef>

// ---------------- problem constants ----------------
constexpr int NNODES = 50000;
constexpr int NEDGES = 500000;
constexpr int NRELS  = 8;
constexpr int DIM    = 128;
constexpr int ADIM   = 64;
constexpr int TWOD   = 256;
constexpr int EPB    = 64;
constexpr float SLOPE = 0.01f;

constexpr int XPITCH = TWOD + 8;   // k_out only
constexpr int SPAD = NEDGES + 1024;

typedef __attribute__((ext_vector_type(8))) short short8;
typedef __attribute__((ext_vector_type(4))) float floatx4;

__device__ __forceinline__ unsigned short f2bf(float f) {
    unsigned u = __float_as_uint(f);
    unsigned r = u + 0x7FFFu + ((u >> 16) & 1u);
    return (unsigned short)(r >> 16);
}
__device__ __forceinline__ float bf2f(unsigned short b) {
    return __uint_as_float(((unsigned)b) << 16);
}
// v_rcp_f32-based sigmoid: avoids the ~10-instr correctly-rounded div sequence.
__device__ __forceinline__ float sigmoid_fast(float x) {
    return __builtin_amdgcn_rcpf(1.0f + __expf(-x));
}

// ---------------- init (histD/cursorD/cnts only; sMeta pads filled in k_scan) ----------------
__global__ void k_init(int* __restrict__ histD, int* __restrict__ cursorD,
                       int* __restrict__ cnts) {
    int i = blockIdx.x * blockDim.x + threadIdx.x;
    int stride = gridDim.x * blockDim.x;
    for (int idx = i; idx < NNODES; idx += stride) { histD[idx] = 0; cursorD[idx] = 0; }
    if (i < 16) cnts[i] = 0;
}

// ---------------- prep: relT transpose via LDS tile; Wl/Wa16 linear ----------------
__global__ __launch_bounds__(256) void k_prep(const float* __restrict__ rel,
                                              const float* __restrict__ W_lin,
                                              const float* __restrict__ W_a,
                                              unsigned short* __restrict__ relT,
                                              unsigned short* __restrict__ Wl,
                                              unsigned short* __restrict__ Wa16) {
    __shared__ float ls[64][65];
    int b = blockIdx.x, t = threadIdx.x;
    if (b < 64) {
        int r = b >> 3, tile = b & 7;
        int d0 = (tile >> 1) * 64, o0 = (tile & 1) * 64;
        const float* rp = rel + ((size_t)r * TWOD + d0) * DIM + o0;
#pragma unroll
        for (int u = 0; u < 16; u++) {
            int v = u * 256 + t;
            int j = v & 63, i = v >> 6;
            ls[i][j] = rp[(size_t)i * DIM + j];
        }
        __syncthreads();
        unsigned short* wp = relT + ((size_t)r * DIM + o0) * TWOD + d0;
#pragma unroll
        for (int u = 0; u < 16; u++) {
            int v = u * 256 + t;
            int ii = v & 63, jj = v >> 6;
            wp[(size_t)jj * TWOD + ii] = f2bf(ls[ii][jj]);
        }
    } else {
        int idx = (b - 64) * 256 + t;
        if (idx < DIM * TWOD) {
            Wl[idx] = f2bf(W_lin[idx]);
        } else {
            int j = idx - DIM * TWOD;
            if (j < ADIM * TWOD) Wa16[j] = f2bf(W_a[j]);
        }
    }
}

// ---------------- h -> bf16 ----------------
__global__ void k_h16(const float* __restrict__ h, unsigned short* __restrict__ h16) {
    int i = blockIdx.x * 256 + threadIdx.x;
    if (i < NNODES * DIM / 8) {
        const float4* hp = (const float4*)(h + (size_t)i * 8);
        float4 a = hp[0], b = hp[1];
        union { unsigned short us[8]; short8 s8; } pk;
        pk.us[0] = f2bf(a.x); pk.us[1] = f2bf(a.y); pk.us[2] = f2bf(a.z); pk.us[3] = f2bf(a.w);
        pk.us[4] = f2bf(b.x); pk.us[5] = f2bf(b.y); pk.us[6] = f2bf(b.z); pk.us[7] = f2bf(b.w);
        *(short8*)&h16[(size_t)i * 8] = pk.s8;
    }
}

// ---------------- fused histogram ----------------
__global__ void k_hist2(const int* __restrict__ ety, const int* __restrict__ dst,
                        int* __restrict__ cnt, int* __restrict__ histD) {
    __shared__ int hist[NRELS];
    int t = threadIdx.x;
    if (t < NRELS) hist[t] = 0;
    __syncthreads();
    int e = blockIdx.x * 256 + t;
    if (e < NEDGES) {
        atomicAdd(&hist[ety[e]], 1);
        atomicAdd(&histD[dst[e]], 1);
    }
    __syncthreads();
    if (t < NRELS && hist[t] > 0) atomicAdd(&cnt[t], hist[t]);
}

// ---------------- scan (+ bucket-tail pad fill for sMeta) ----------------
__global__ __launch_bounds__(1024) void k_scan(const int* __restrict__ histD,
                                               int* __restrict__ row_ptr,
                                               const int* __restrict__ cnt,
                                               int* __restrict__ offs,
                                               uint2* __restrict__ sMeta) {
    __shared__ int ls[1024];
    __shared__ int s_offs[NRELS + 1];
    __shared__ int s_cnt[NRELS];
    const int t = threadIdx.x;
    const int CH = (NNODES + 1023) / 1024;
    const int base = t * CH;
    int s = 0;
    for (int j = 0; j < CH; j++) { int i = base + j; if (i < NNODES) s += histD[i]; }
    ls[t] = s;
    __syncthreads();
    for (int off = 1; off < 1024; off <<= 1) {
        int v = (t >= off) ? ls[t - off] : 0;
        __syncthreads();
        ls[t] += v;
        __syncthreads();
    }
    int run = (t == 0) ? 0 : ls[t - 1];
    for (int j = 0; j < CH; j++) {
        int i = base + j;
        if (i < NNODES) { row_ptr[i] = run; run += histD[i]; }
    }
    if (t == 1023) row_ptr[NNODES] = ls[1023];
    if (t == 0) {
        int off = 0;
        for (int r = 0; r < NRELS; r++) {
            offs[r] = off; s_offs[r] = off; s_cnt[r] = cnt[r];
            off += ((cnt[r] + EPB - 1) / EPB) * EPB;
        }
        s_offs[NRELS] = off;
    }
    __syncthreads();
    // fill pad slots (bucket tails + global tail) with invalid markers
#pragma unroll
    for (int r = 0; r < NRELS; r++) {
        int s0 = s_offs[r] + s_cnt[r];
        int e0 = s_offs[r + 1 > NRELS ? NRELS : r + 1];
        for (int idx = s0 + t; idx < e0; idx += 1024) sMeta[idx] = make_uint2(0xFFFFFFFFu, 0u);
    }
    for (int idx = s_offs[NRELS] + t; idx < SPAD; idx += 1024)
        sMeta[idx] = make_uint2(0xFFFFFFFFu, 0u);
}

// ---------------- single-pass scatter: dst-CSR position + etype bucket slot ----------------
__global__ void k_escatter(const int* __restrict__ ety, const int* __restrict__ src,
                           const int* __restrict__ dst, const int* __restrict__ row_ptr,
                           const int* __restrict__ offs,
                           int* __restrict__ cursorD, int* __restrict__ cursorE,
                           uint2* __restrict__ sMeta) {
    __shared__ int hist[NRELS];
    __shared__ int basew[NRELS];
    int t = threadIdx.x;
    if (t < NRELS) hist[t] = 0;
    __syncthreads();
    int e = blockIdx.x * 256 + t;
    int r = -1, rank = 0, sn = 0, dn = 0;
    if (e < NEDGES) {
        r = ety[e]; sn = src[e]; dn = dst[e];
        rank = atomicAdd(&hist[r], 1);
    }
    __syncthreads();
    if (t < NRELS && hist[t] > 0) basew[t] = atomicAdd(&cursorE[t], hist[t]);
    __syncthreads();
    if (e < NEDGES) {
        int s = offs[r] + basew[r] + rank;
        int pos = row_ptr[dn] + atomicAdd(&cursorD[dn], 1);
        sMeta[s] = make_uint2((unsigned)sn | ((unsigned)dn << 16), (unsigned)pos);
    }
}

// ---------------- gates + messages + scores: single merged MFMA K-loop ----------------
// LDS = exactly 32768 B (Xs only, XOR-swizzled 16B units) -> 5 blocks/CU.
// Meta lives in registers (one edge per lane of each wave) + __shfl broadcast.
// scoreW aliased into the Xs src-half (dead after gate epilogue).
__global__ __launch_bounds__(256, 5) void k_gate_msg(
    const unsigned short* __restrict__ h16, const unsigned short* __restrict__ relT,
    const unsigned short* __restrict__ Wa16,
    const uint2* __restrict__ sMeta, const float* __restrict__ b_a,
    const float* __restrict__ ratt, const int* __restrict__ offs,
    unsigned short* __restrict__ msgbuf, float* __restrict__ scoreP) {
    __shared__ unsigned short Xs[EPB * 256];   // 32768 B exactly

    const int t = threadIdx.x;
    const int base = blockIdx.x * EPB;
    const int lane = t & 63;
    const int wave = t >> 6;

    // each wave holds all 64 edges' meta, one per lane
    uint2 sm = sMeta[base + lane];
    const unsigned smx = sm.x;
    const unsigned smy = sm.y;

    if (__shfl((int)smx, 0) == -1) return;   // fully-pad block

    int r = 0;
#pragma unroll
    for (int i = 1; i < NRELS; i++) if (base >= offs[i]) r = i;

    // gather: row i = u*8 + t/32, 16B unit c = t&31; swizzle u' = c ^ (i&7)
#pragma unroll
    for (int u = 0; u < 8; u++) {
        int i = u * 8 + (t >> 5);
        int c = t & 31;
        unsigned x = (unsigned)__shfl((int)smx, i);
        int node = (x == 0xFFFFFFFFu) ? 0 : ((c < 16) ? (int)(x >> 16) : (int)(x & 0xFFFFu));
        *(short8*)&Xs[i * 256 + ((c ^ (i & 7)) << 3)] =
            *(const short8*)&h16[(size_t)node * DIM + (c & 15) * 8];
    }

    const int q = lane >> 4;
    const int l16 = lane & 15;
    const int o16 = wave * 16 + l16;

    const unsigned short* bp0 = relT + ((size_t)r * DIM + (wave * 2 + 0) * 16 + l16) * TWOD + q * 8;
    const unsigned short* bp1 = relT + ((size_t)r * DIM + (wave * 2 + 1) * 16 + l16) * TWOD + q * 8;
    const unsigned short* wb  = Wa16 + (size_t)o16 * TWOD + q * 8;

    __syncthreads();   // A: gather complete

    floatx4 acc[4][2];
    floatx4 accS[4];
#pragma unroll
    for (int m = 0; m < 4; m++) {
        acc[m][0] = (floatx4)(0.0f);
        acc[m][1] = (floatx4)(0.0f);
        accS[m] = (floatx4)(0.0f);
    }

#pragma unroll
    for (int ks = 0; ks < 8; ks++) {
        short8 B0 = *(const short8*)(bp0 + ks * 32);
        short8 B1 = *(const short8*)(bp1 + ks * 32);
        short8 BS = *(const short8*)(wb + ks * 32);
        short8 Af[4];
#pragma unroll
        for (int m = 0; m < 4; m++) {
            int row = m * 16 + l16;
            Af[m] = *(const short8*)&Xs[row * 256 + ((((ks * 4) + q) ^ (l16 & 7)) << 3)];
        }
#pragma unroll
        for (int m = 0; m < 4; m++) {
            acc[m][0] = __builtin_amdgcn_mfma_f32_16x16x32_bf16(Af[m], B0, acc[m][0], 0, 0, 0);
            acc[m][1] = __builtin_amdgcn_mfma_f32_16x16x32_bf16(Af[m], B1, acc[m][1], 0, 0, 0);
            accS[m]   = __builtin_amdgcn_mfma_f32_16x16x32_bf16(Af[m], BS, accS[m], 0, 0, 0);
        }
    }

    __syncthreads();   // B: all MFMA A-reads done before dst-half overwrite

    // gate epilogue: msg = sigmoid(acc) * src_h -> Xs dst half (bf16)
#pragma unroll
    for (int m = 0; m < 4; m++) {
        int ib = m * 16 + q * 4;
#pragma unroll
        for (int nn = 0; nn < 2; nn++) {
            int o = (wave * 2 + nn) * 16 + l16;
            int uS = 16 + (o >> 3), uD = o >> 3, ofs = o & 7;
#pragma unroll
            for (int rg = 0; rg < 4; rg++) {
                int i = ib + rg;
                float g = sigmoid_fast(acc[m][nn][rg]);
                float sh = bf2f(Xs[i * 256 + ((uS ^ (i & 7)) << 3) + ofs]);
                Xs[i * 256 + ((uD ^ (i & 7)) << 3) + ofs] = f2bf(sh * g);
            }
        }
    }
    __syncthreads();   // C: dst writes done, src reads done (src half now dead)

    // score epilogue -> scoreW aliased at phys unit 16 (src-half) of each row
    {
        float ba = b_a[o16];
        float ra = ratt[o16];
#pragma unroll
        for (int m = 0; m < 4; m++) {
#pragma unroll
            for (int rg = 0; rg < 4; rg++) {
                float v = accS[m][rg] + ba;
                v = v > 0.0f ? v : SLOPE * v;
                v *= ra;
#pragma unroll
                for (int off = 8; off > 0; off >>= 1) v += __shfl_xor(v, off, 16);
                if (l16 == 0) ((float*)&Xs[(m * 16 + q * 4 + rg) * 256 + 128])[wave] = v;
            }
        }
    }

    // msgbuf store: reads dst half (written before barrier C)
#pragma unroll
    for (int u = 0; u < 4; u++) {
        int i = u * 16 + (t >> 4);
        int c = t & 15;
        unsigned x = (unsigned)__shfl((int)smx, i);
        unsigned pos = (unsigned)__shfl((int)smy, i);
        if (x == 0xFFFFFFFFu) continue;
        short8 val = *(const short8*)&Xs[i * 256 + ((c ^ (i & 7)) << 3)];
        *(short8*)&msgbuf[(size_t)pos * DIM + c * 8] = val;
    }
    __syncthreads();   // D: scoreW visible

    if (t < EPB && smx != 0xFFFFFFFFu) {
        const float* sw = (const float*)&Xs[t * 256 + 128];
        scoreP[smy] = sw[0] + sw[1] + sw[2] + sw[3];
    }
}

// ---------------- fused softmax + weighted segment-sum -> hN bf16 ----------------
__global__ __launch_bounds__(256) void k_aggr(const unsigned short* __restrict__ msgbuf,
                                              const float* __restrict__ scoreP,
                                              const int* __restrict__ row_ptr,
                                              unsigned short* __restrict__ hN16) {
    int n = blockIdx.x * 4 + (threadIdx.x >> 6);
    int lane = threadIdx.x & 63;
    if (n >= NNODES) return;
    int p0 = row_ptr[n], p1 = row_ptr[n + 1];
    float a0 = 0.0f, a1 = 0.0f;
    if (p0 < p1) {
        float mx = -3.0e38f;
        for (int p = p0 + lane; p < p1; p += 64) mx = fmaxf(mx, scoreP[p]);
#pragma unroll
        for (int off = 32; off > 0; off >>= 1) mx = fmaxf(mx, __shfl_xor(mx, off));
        float sum = 0.0f;
        for (int p = p0 + lane; p < p1; p += 64) sum += __expf(scoreP[p] - mx);
#pragma unroll
        for (int off = 32; off > 0; off >>= 1) sum += __shfl_xor(sum, off);
        // weighted stream, 4-deep unrolled for MLP; 1/sum applied once at the end
        int p = p0;
        const unsigned short* mb = msgbuf + (size_t)lane * 2;
        for (; p + 4 <= p1; p += 4) {
            float w0 = __expf(scoreP[p + 0] - mx);
            float w1 = __expf(scoreP[p + 1] - mx);
            float w2 = __expf(scoreP[p + 2] - mx);
            float w3 = __expf(scoreP[p + 3] - mx);
            unsigned v0 = *(const unsigned*)&mb[(size_t)(p + 0) * DIM];
            unsigned v1 = *(const unsigned*)&mb[(size_t)(p + 1) * DIM];
            unsigned v2 = *(const unsigned*)&mb[(size_t)(p + 2) * DIM];
            unsigned v3 = *(const unsigned*)&mb[(size_t)(p + 3) * DIM];
            a0 = fmaf(w0, bf2f((unsigned short)(v0 & 0xFFFFu)), a0);
            a1 = fmaf(w0, bf2f((unsigned short)(v0 >> 16)), a1);
            a0 = fmaf(w1, bf2f((unsigned short)(v1 & 0xFFFFu)), a0);
            a1 = fmaf(w1, bf2f((unsigned short)(v1 >> 16)), a1);
            a0 = fmaf(w2, bf2f((unsigned short)(v2 & 0xFFFFu)), a0);
            a1 = fmaf(w2, bf2f((unsigned short)(v2 >> 16)), a1);
            a0 = fmaf(w3, bf2f((unsigned short)(v3 & 0xFFFFu)), a0);
            a1 = fmaf(w3, bf2f((unsigned short)(v3 >> 16)), a1);
        }
        for (; p < p1; p++) {
            float w = __expf(scoreP[p] - mx);
            unsigned v = *(const unsigned*)&mb[(size_t)p * DIM];
            a0 = fmaf(w, bf2f((unsigned short)(v & 0xFFFFu)), a0);
            a1 = fmaf(w, bf2f((unsigned short)(v >> 16)), a1);
        }
        float inv = __builtin_amdgcn_rcpf(sum);
        a0 *= inv; a1 *= inv;
    }
    unsigned o = (unsigned)f2bf(a0) | ((unsigned)f2bf(a1) << 16);
    *(unsigned*)&hN16[(size_t)n * DIM + lane * 2] = o;
}

// ---------------- out = leaky(W_lin @ [h ; h_N] + b) via MFMA ----------------
__global__ __launch_bounds__(256) void k_out(const unsigned short* __restrict__ h16,
                                             const unsigned short* __restrict__ hN16,
                                             const unsigned short* __restrict__ Wl,
                                             const float* __restrict__ b_lin,
                                             float* __restrict__ out) {
    __shared__ unsigned short Xs[EPB * XPITCH];
    const int t = threadIdx.x;
    const int nb = blockIdx.x * 64;

#pragma unroll
    for (int u = 0; u < 8; u++) {
        int v = u * 256 + t;
        int i = v >> 5;
        int c = v & 31;
        int n = nb + i;
        if (n >= NNODES) n = NNODES - 1;
        const unsigned short* srcp = (c < 16) ? h16 : hN16;
        *(short8*)&Xs[i * XPITCH + c * 8] = *(const short8*)&srcp[(size_t)n * DIM + (c & 15) * 8];
    }

    const int wave = t >> 6;
    const int lane = t & 63;
    const int q = lane >> 4;
    const int l16 = lane & 15;

    short8 Bf[2][8];
#pragma unroll
    for (int nn = 0; nn < 2; nn++) {
        int o = (wave * 2 + nn) * 16 + l16;
        const unsigned short* bp = Wl + (size_t)o * TWOD + q * 8;
#pragma unroll
        for (int ks = 0; ks < 8; ks++) Bf[nn][ks] = *(const short8*)(bp + ks * 32);
    }

    __syncthreads();

    floatx4 acc[4][2];
#pragma unroll
    for (int m = 0; m < 4; m++)
#pragma unroll
        for (int nn = 0; nn < 2; nn++) acc[m][nn] = (floatx4)(0.0f);

#pragma unroll
    for (int ks = 0; ks < 8; ks++) {
        short8 Af[4];
        const unsigned short* xb = &Xs[l16 * XPITCH + ks * 32 + q * 8];
#pragma unroll
        for (int m = 0; m < 4; m++) Af[m] = *(const short8*)(xb + m * 16 * XPITCH);
#pragma unroll
        for (int m = 0; m < 4; m++)
#pragma unroll
            for (int nn = 0; nn < 2; nn++)
                acc[m][nn] = __builtin_amdgcn_mfma_f32_16x16x32_bf16(Af[m], Bf[nn][ks], acc[m][nn], 0, 0, 0);
    }

#pragma unroll
    for (int m = 0; m < 4; m++) {
        int ib = m * 16 + q * 4;
#pragma unroll
        for (int nn = 0; nn < 2; nn++) {
            int o = (wave * 2 + nn) * 16 + l16;
            float bl = b_lin[o];
#pragma unroll
            for (int rg = 0; rg < 4; rg++) {
                int n = nb + ib + rg;
                if (n < NNODES) {
                    float val = acc[m][nn][rg] + bl;
                    val = val > 0.0f ? val : SLOPE * val;
                    out[(size_t)n * DIM + o] = val;
                }
            }
        }
    }
}

// ---------------- launcher ----------------
extern "C" void kernel_launch(void* const* d_in, const int* in_sizes, int n_in,
                              void* d_out, int out_size, void* d_ws, size_t ws_size,
                              hipStream_t stream) {
    const float* h     = (const float*)d_in[0];
    const float* rel   = (const float*)d_in[1];
    const float* ratt  = (const float*)d_in[2];
    const float* W_a   = (const float*)d_in[3];
    const float* b_a   = (const float*)d_in[4];
    const float* W_lin = (const float*)d_in[5];
    const float* b_lin = (const float*)d_in[6];
    const int* src = (const int*)d_in[7];
    const int* dst = (const int*)d_in[8];
    const int* ety = (const int*)d_in[9];
    float* out = (float*)d_out;

    // workspace layout (~161 MB)
    float* scoreP = (float*)d_ws;                                   // E
    unsigned short* h16  = (unsigned short*)(scoreP + NEDGES);      // N*128 bf16
    unsigned short* hN16 = h16 + (size_t)NNODES * DIM;              // N*128 bf16
    unsigned short* relT = hN16 + (size_t)NNODES * DIM;             // 8*128*256 bf16
    unsigned short* Wl   = relT + (size_t)NRELS * DIM * TWOD;       // 128*256 bf16
    unsigned short* Wa16 = Wl + (size_t)DIM * TWOD;                 // 64*256 bf16
    uint2* sMeta = (uint2*)(Wa16 + (size_t)ADIM * TWOD);            // SPAD uint2
    int* row_ptr = (int*)(sMeta + SPAD);                            // N+1
    int* histD   = row_ptr + (NNODES + 1);                          // N
    int* cursorD = histD + NNODES;                                  // N
    int* cnts    = cursorD + NNODES;                                // 16
    int* offs    = cnts + 16;                                       // 8
    unsigned short* msgbuf = (unsigned short*)(((uintptr_t)(offs + 8) + 255) & ~(uintptr_t)255); // E*128 bf16

    k_init<<<256, 256, 0, stream>>>(histD, cursorD, cnts);
    k_prep<<<64 + (DIM * TWOD + ADIM * TWOD + 255) / 256, 256, 0, stream>>>(
        rel, W_lin, W_a, relT, Wl, Wa16);
    k_h16<<<(NNODES * DIM / 8 + 255) / 256, 256, 0, stream>>>(h, h16);
    k_hist2<<<(NEDGES + 255) / 256, 256, 0, stream>>>(ety, dst, cnts, histD);
    k_scan<<<1, 1024, 0, stream>>>(histD, row_ptr, cnts, offs, sMeta);
    k_escatter<<<(NEDGES + 255) / 256, 256, 0, stream>>>(
        ety, src, dst, row_ptr, offs, cursorD, cnts + 8, sMeta);
    k_gate_msg<<<(NEDGES + 8 * EPB + EPB - 1) / EPB, 256, 0, stream>>>(
        h16, relT, Wa16, sMeta, b_a, ratt, offs, msgbuf, scoreP);
    k_aggr<<<(NNODES + 3) / 4, 256, 0, stream>>>(msgbuf, scoreP, row_ptr, hN16);
    k_out<<<(NNODES + 63) / 64, 256, 0, stream>>>(h16, hN16, Wl, b_lin, out);
}

// Round 3
// 454.521 us; speedup vs baseline: 1.0379x; 1.0101x over previous
//
#include <hip/hip_runtime.h>
#include <cstdint>
#include <cstddef>

// ---------------- problem constants ----------------
constexpr int NNODES = 50000;
constexpr int NEDGES = 500000;
constexpr int NRELS  = 8;
constexpr int DIM    = 128;
constexpr int ADIM   = 64;
constexpr int TWOD   = 256;
constexpr int EPB    = 64;
constexpr float SLOPE = 0.01f;

constexpr int XPITCH = TWOD + 8;   // k_out only
constexpr int SPAD = NEDGES + 1024;

typedef __attribute__((ext_vector_type(8))) short short8;
typedef __attribute__((ext_vector_type(4))) float floatx4;

__device__ __forceinline__ unsigned short f2bf(float f) {
    unsigned u = __float_as_uint(f);
    unsigned r = u + 0x7FFFu + ((u >> 16) & 1u);
    return (unsigned short)(r >> 16);
}
__device__ __forceinline__ float bf2f(unsigned short b) {
    return __uint_as_float(((unsigned)b) << 16);
}
// v_rcp_f32-based sigmoid: avoids the ~10-instr correctly-rounded div sequence.
__device__ __forceinline__ float sigmoid_fast(float x) {
    return __builtin_amdgcn_rcpf(1.0f + __expf(-x));
}

// direct global->LDS 16B copy (dest = uniform base + lane*16)
typedef const __attribute__((address_space(1))) void* gas_ptr;
typedef __attribute__((address_space(3))) void* las_ptr;
__device__ __forceinline__ void gload_lds16(const void* g, void* l) {
    __builtin_amdgcn_global_load_lds((gas_ptr)g, (las_ptr)l, 16, 0, 0);
}

// ---------------- init (histD/cursorD/cnts only; sMeta pads filled in k_scan) ----------------
__global__ void k_init(int* __restrict__ histD, int* __restrict__ cursorD,
                       int* __restrict__ cnts) {
    int i = blockIdx.x * blockDim.x + threadIdx.x;
    int stride = gridDim.x * blockDim.x;
    for (int idx = i; idx < NNODES; idx += stride) { histD[idx] = 0; cursorD[idx] = 0; }
    if (i < 16) cnts[i] = 0;
}

// ---------------- prep: relT transpose via LDS tile; Wl/Wa16 linear ----------------
__global__ __launch_bounds__(256) void k_prep(const float* __restrict__ rel,
                                              const float* __restrict__ W_lin,
                                              const float* __restrict__ W_a,
                                              unsigned short* __restrict__ relT,
                                              unsigned short* __restrict__ Wl,
                                              unsigned short* __restrict__ Wa16) {
    __shared__ float ls[64][65];
    int b = blockIdx.x, t = threadIdx.x;
    if (b < 64) {
        int r = b >> 3, tile = b & 7;
        int d0 = (tile >> 1) * 64, o0 = (tile & 1) * 64;
        const float* rp = rel + ((size_t)r * TWOD + d0) * DIM + o0;
#pragma unroll
        for (int u = 0; u < 16; u++) {
            int v = u * 256 + t;
            int j = v & 63, i = v >> 6;
            ls[i][j] = rp[(size_t)i * DIM + j];
        }
        __syncthreads();
        unsigned short* wp = relT + ((size_t)r * DIM + o0) * TWOD + d0;
#pragma unroll
        for (int u = 0; u < 16; u++) {
            int v = u * 256 + t;
            int ii = v & 63, jj = v >> 6;
            wp[(size_t)jj * TWOD + ii] = f2bf(ls[ii][jj]);
        }
    } else {
        int idx = (b - 64) * 256 + t;
        if (idx < DIM * TWOD) {
            Wl[idx] = f2bf(W_lin[idx]);
        } else {
            int j = idx - DIM * TWOD;
            if (j < ADIM * TWOD) Wa16[j] = f2bf(W_a[j]);
        }
    }
}

// ---------------- h -> bf16 ----------------
__global__ void k_h16(const float* __restrict__ h, unsigned short* __restrict__ h16) {
    int i = blockIdx.x * 256 + threadIdx.x;
    if (i < NNODES * DIM / 8) {
        const float4* hp = (const float4*)(h + (size_t)i * 8);
        float4 a = hp[0], b = hp[1];
        union { unsigned short us[8]; short8 s8; } pk;
        pk.us[0] = f2bf(a.x); pk.us[1] = f2bf(a.y); pk.us[2] = f2bf(a.z); pk.us[3] = f2bf(a.w);
        pk.us[4] = f2bf(b.x); pk.us[5] = f2bf(b.y); pk.us[6] = f2bf(b.z); pk.us[7] = f2bf(b.w);
        *(short8*)&h16[(size_t)i * 8] = pk.s8;
    }
}

// ---------------- fused histogram ----------------
__global__ void k_hist2(const int* __restrict__ ety, const int* __restrict__ dst,
                        int* __restrict__ cnt, int* __restrict__ histD) {
    __shared__ int hist[NRELS];
    int t = threadIdx.x;
    if (t < NRELS) hist[t] = 0;
    __syncthreads();
    int e = blockIdx.x * 256 + t;
    if (e < NEDGES) {
        atomicAdd(&hist[ety[e]], 1);
        atomicAdd(&histD[dst[e]], 1);
    }
    __syncthreads();
    if (t < NRELS && hist[t] > 0) atomicAdd(&cnt[t], hist[t]);
}

// ---------------- scan (+ bucket-tail pad fill for sMeta) ----------------
__global__ __launch_bounds__(1024) void k_scan(const int* __restrict__ histD,
                                               int* __restrict__ row_ptr,
                                               const int* __restrict__ cnt,
                                               int* __restrict__ offs,
                                               uint2* __restrict__ sMeta) {
    __shared__ int ls[1024];
    __shared__ int s_offs[NRELS + 1];
    __shared__ int s_cnt[NRELS];
    const int t = threadIdx.x;
    const int CH = (NNODES + 1023) / 1024;
    const int base = t * CH;
    int s = 0;
    for (int j = 0; j < CH; j++) { int i = base + j; if (i < NNODES) s += histD[i]; }
    ls[t] = s;
    __syncthreads();
    for (int off = 1; off < 1024; off <<= 1) {
        int v = (t >= off) ? ls[t - off] : 0;
        __syncthreads();
        ls[t] += v;
        __syncthreads();
    }
    int run = (t == 0) ? 0 : ls[t - 1];
    for (int j = 0; j < CH; j++) {
        int i = base + j;
        if (i < NNODES) { row_ptr[i] = run; run += histD[i]; }
    }
    if (t == 1023) row_ptr[NNODES] = ls[1023];
    if (t == 0) {
        int off = 0;
        for (int r = 0; r < NRELS; r++) {
            offs[r] = off; s_offs[r] = off; s_cnt[r] = cnt[r];
            off += ((cnt[r] + EPB - 1) / EPB) * EPB;
        }
        s_offs[NRELS] = off;
    }
    __syncthreads();
    // fill pad slots (bucket tails + global tail) with invalid markers
#pragma unroll
    for (int r = 0; r < NRELS; r++) {
        int s0 = s_offs[r] + s_cnt[r];
        int e0 = s_offs[r + 1 > NRELS ? NRELS : r + 1];
        for (int idx = s0 + t; idx < e0; idx += 1024) sMeta[idx] = make_uint2(0xFFFFFFFFu, 0u);
    }
    for (int idx = s_offs[NRELS] + t; idx < SPAD; idx += 1024)
        sMeta[idx] = make_uint2(0xFFFFFFFFu, 0u);
}

// ---------------- single-pass scatter: dst-CSR position + etype bucket slot ----------------
__global__ void k_escatter(const int* __restrict__ ety, const int* __restrict__ src,
                           const int* __restrict__ dst, const int* __restrict__ row_ptr,
                           const int* __restrict__ offs,
                           int* __restrict__ cursorD, int* __restrict__ cursorE,
                           uint2* __restrict__ sMeta) {
    __shared__ int hist[NRELS];
    __shared__ int basew[NRELS];
    int t = threadIdx.x;
    if (t < NRELS) hist[t] = 0;
    __syncthreads();
    int e = blockIdx.x * 256 + t;
    int r = -1, rank = 0, sn = 0, dn = 0;
    if (e < NEDGES) {
        r = ety[e]; sn = src[e]; dn = dst[e];
        rank = atomicAdd(&hist[r], 1);
    }
    __syncthreads();
    if (t < NRELS && hist[t] > 0) basew[t] = atomicAdd(&cursorE[t], hist[t]);
    __syncthreads();
    if (e < NEDGES) {
        int s = offs[r] + basew[r] + rank;
        int pos = row_ptr[dn] + atomicAdd(&cursorD[dn], 1);
        sMeta[s] = make_uint2((unsigned)sn | ((unsigned)dn << 16), (unsigned)pos);
    }
}

// ---------------- gates + messages + scores: single merged MFMA K-loop ----------------
// Gather: global_load_lds direct (no VGPR round-trip, no ds_writes). LDS layout is
// linear in hardware order (dest = base + lane*16); the XOR unit-swizzle
// (physical = logical ^ (row&7)) is folded into the per-lane GLOBAL source
// address, so MFMA A-reads are bank-spread without a pitch pad.
// Meta in LDS arrays (broadcast ds_read, no ds_bpermute chains).
__global__ __launch_bounds__(256, 4) void k_gate_msg(
    const unsigned short* __restrict__ h16, const unsigned short* __restrict__ relT,
    const unsigned short* __restrict__ Wa16,
    const uint2* __restrict__ sMeta, const float* __restrict__ b_a,
    const float* __restrict__ ratt, const int* __restrict__ offs,
    unsigned short* __restrict__ msgbuf, float* __restrict__ scoreP) {
    __shared__ unsigned short Xs[EPB * 256];   // 32768 B
    __shared__ int srcn_s[EPB];
    __shared__ int dstn_s[EPB];
    __shared__ int pos_s[EPB];
    __shared__ int val_s[EPB];
    __shared__ float scoreW[EPB][4];

    const int t = threadIdx.x;
    const int base = blockIdx.x * EPB;
    const int lane = t & 63;
    const int wave = t >> 6;

    if (t < EPB) {
        uint2 m2 = sMeta[base + t];
        int valid = (m2.x != 0xFFFFFFFFu);
        val_s[t] = valid;
        srcn_s[t] = valid ? (int)(m2.x & 0xFFFFu) : 0;
        dstn_s[t] = valid ? (int)(m2.x >> 16) : 0;
        pos_s[t] = valid ? (int)m2.y : 0;
    }
    __syncthreads();
    if (!val_s[0]) return;

    int r = 0;
#pragma unroll
    for (int i = 1; i < NRELS; i++) if (base >= offs[i]) r = i;

    // gather: iteration j = wave*8+u covers rows 2j, 2j+1 (64 lanes x 16B).
    // lane writes physical unit p = lane&31 of row 2j+(lane>>5); it must carry
    // the data of logical unit lu = p ^ (row&7).
#pragma unroll
    for (int u = 0; u < 8; u++) {
        int j = wave * 8 + u;
        int row = j * 2 + (lane >> 5);
        int lu = (lane & 31) ^ (row & 7);
        int node = (lu < 16) ? dstn_s[row] : srcn_s[row];
        gload_lds16(&h16[(size_t)node * DIM + (lu & 15) * 8], &Xs[j * 512]);
    }

    const int q = lane >> 4;
    const int l16 = lane & 15;
    const int o16 = wave * 16 + l16;

    const unsigned short* bp0 = relT + ((size_t)r * DIM + (wave * 2 + 0) * 16 + l16) * TWOD + q * 8;
    const unsigned short* bp1 = relT + ((size_t)r * DIM + (wave * 2 + 1) * 16 + l16) * TWOD + q * 8;
    const unsigned short* wb  = Wa16 + (size_t)o16 * TWOD + q * 8;

    // prefetch B0 for all 8 K-groups; pin with empty asm so the compiler cannot
    // sink the loads past the barrier (their L2 fetch overlaps the gather drain)
    short8 B0p[8];
#pragma unroll
    for (int ks = 0; ks < 8; ks++) B0p[ks] = *(const short8*)(bp0 + ks * 32);
#pragma unroll
    for (int ks = 0; ks < 8; ks++) asm volatile("" :: "v"(B0p[ks]));

    __syncthreads();   // A: gather complete

    floatx4 acc[4][2];
    floatx4 accS[4];
#pragma unroll
    for (int m = 0; m < 4; m++) {
        acc[m][0] = (floatx4)(0.0f);
        acc[m][1] = (floatx4)(0.0f);
        accS[m] = (floatx4)(0.0f);
    }

#pragma unroll
    for (int ks = 0; ks < 8; ks++) {
        short8 B0 = B0p[ks];
        short8 B1 = *(const short8*)(bp1 + ks * 32);
        short8 BS = *(const short8*)(wb + ks * 32);
        short8 Af[4];
#pragma unroll
        for (int m = 0; m < 4; m++) {
            int row = m * 16 + l16;
            Af[m] = *(const short8*)&Xs[row * 256 + ((((ks * 4) + q) ^ (l16 & 7)) << 3)];
        }
#pragma unroll
        for (int m = 0; m < 4; m++) {
            acc[m][0] = __builtin_amdgcn_mfma_f32_16x16x32_bf16(Af[m], B0, acc[m][0], 0, 0, 0);
            acc[m][1] = __builtin_amdgcn_mfma_f32_16x16x32_bf16(Af[m], B1, acc[m][1], 0, 0, 0);
            accS[m]   = __builtin_amdgcn_mfma_f32_16x16x32_bf16(Af[m], BS, accS[m], 0, 0, 0);
        }
    }

    __syncthreads();   // B: all MFMA A-reads done before dst-half overwrite

    // score epilogue (regs -> scoreW; no Xs traffic)
    {
        float ba = b_a[o16];
        float ra = ratt[o16];
#pragma unroll
        for (int m = 0; m < 4; m++) {
#pragma unroll
            for (int rg = 0; rg < 4; rg++) {
                float v = accS[m][rg] + ba;
                v = v > 0.0f ? v : SLOPE * v;
                v *= ra;
#pragma unroll
                for (int off = 8; off > 0; off >>= 1) v += __shfl_xor(v, off, 16);
                if (l16 == 0) scoreW[m * 16 + q * 4 + rg][wave] = v;
            }
        }
    }

    // gate epilogue: msg = sigmoid(acc) * src_h -> Xs dst half (bf16), column-partitioned
#pragma unroll
    for (int m = 0; m < 4; m++) {
        int ib = m * 16 + q * 4;
#pragma unroll
        for (int nn = 0; nn < 2; nn++) {
            int o = (wave * 2 + nn) * 16 + l16;
            int uS = 16 + (o >> 3), uD = o >> 3, ofs = o & 7;
#pragma unroll
            for (int rg = 0; rg < 4; rg++) {
                int i = ib + rg;
                float g = sigmoid_fast(acc[m][nn][rg]);
                float sh = bf2f(Xs[i * 256 + ((uS ^ (i & 7)) << 3) + ofs]);
                Xs[i * 256 + ((uD ^ (i & 7)) << 3) + ofs] = f2bf(sh * g);
            }
        }
    }
    __syncthreads();   // C: epilogues done

#pragma unroll
    for (int u = 0; u < 4; u++) {
        int v = u * 256 + t;
        int i = v >> 4;
        int c = v & 15;
        if (!val_s[i]) continue;
        short8 val = *(const short8*)&Xs[i * 256 + ((c ^ (i & 7)) << 3)];
        *(short8*)&msgbuf[(size_t)pos_s[i] * DIM + c * 8] = val;
    }
    if (t < EPB && val_s[t]) {
        scoreP[pos_s[t]] = scoreW[t][0] + scoreW[t][1] + scoreW[t][2] + scoreW[t][3];
    }
}

// ---------------- fused softmax + weighted segment-sum -> hN bf16 ----------------
__global__ __launch_bounds__(256) void k_aggr(const unsigned short* __restrict__ msgbuf,
                                              const float* __restrict__ scoreP,
                                              const int* __restrict__ row_ptr,
                                              unsigned short* __restrict__ hN16) {
    int n = blockIdx.x * 4 + (threadIdx.x >> 6);
    int lane = threadIdx.x & 63;
    if (n >= NNODES) return;
    int p0 = row_ptr[n], p1 = row_ptr[n + 1];
    float a0 = 0.0f, a1 = 0.0f;
    if (p0 < p1) {
        float mx = -3.0e38f;
        for (int p = p0 + lane; p < p1; p += 64) mx = fmaxf(mx, scoreP[p]);
#pragma unroll
        for (int off = 32; off > 0; off >>= 1) mx = fmaxf(mx, __shfl_xor(mx, off));
        float sum = 0.0f;
        for (int p = p0 + lane; p < p1; p += 64) sum += __expf(scoreP[p] - mx);
#pragma unroll
        for (int off = 32; off > 0; off >>= 1) sum += __shfl_xor(sum, off);
        // weighted stream, 4-deep unrolled for MLP; 1/sum applied once at the end
        int p = p0;
        const unsigned short* mb = msgbuf + (size_t)lane * 2;
        for (; p + 4 <= p1; p += 4) {
            float w0 = __expf(scoreP[p + 0] - mx);
            float w1 = __expf(scoreP[p + 1] - mx);
            float w2 = __expf(scoreP[p + 2] - mx);
            float w3 = __expf(scoreP[p + 3] - mx);
            unsigned v0 = *(const unsigned*)&mb[(size_t)(p + 0) * DIM];
            unsigned v1 = *(const unsigned*)&mb[(size_t)(p + 1) * DIM];
            unsigned v2 = *(const unsigned*)&mb[(size_t)(p + 2) * DIM];
            unsigned v3 = *(const unsigned*)&mb[(size_t)(p + 3) * DIM];
            a0 = fmaf(w0, bf2f((unsigned short)(v0 & 0xFFFFu)), a0);
            a1 = fmaf(w0, bf2f((unsigned short)(v0 >> 16)), a1);
            a0 = fmaf(w1, bf2f((unsigned short)(v1 & 0xFFFFu)), a0);
            a1 = fmaf(w1, bf2f((unsigned short)(v1 >> 16)), a1);
            a0 = fmaf(w2, bf2f((unsigned short)(v2 & 0xFFFFu)), a0);
            a1 = fmaf(w2, bf2f((unsigned short)(v2 >> 16)), a1);
            a0 = fmaf(w3, bf2f((unsigned short)(v3 & 0xFFFFu)), a0);
            a1 = fmaf(w3, bf2f((unsigned short)(v3 >> 16)), a1);
        }
        for (; p < p1; p++) {
            float w = __expf(scoreP[p] - mx);
            unsigned v = *(const unsigned*)&mb[(size_t)p * DIM];
            a0 = fmaf(w, bf2f((unsigned short)(v & 0xFFFFu)), a0);
            a1 = fmaf(w, bf2f((unsigned short)(v >> 16)), a1);
        }
        float inv = __builtin_amdgcn_rcpf(sum);
        a0 *= inv; a1 *= inv;
    }
    unsigned o = (unsigned)f2bf(a0) | ((unsigned)f2bf(a1) << 16);
    *(unsigned*)&hN16[(size_t)n * DIM + lane * 2] = o;
}

// ---------------- out = leaky(W_lin @ [h ; h_N] + b) via MFMA ----------------
__global__ __launch_bounds__(256) void k_out(const unsigned short* __restrict__ h16,
                                             const unsigned short* __restrict__ hN16,
                                             const unsigned short* __restrict__ Wl,
                                             const float* __restrict__ b_lin,
                                             float* __restrict__ out) {
    __shared__ unsigned short Xs[EPB * XPITCH];
    const int t = threadIdx.x;
    const int nb = blockIdx.x * 64;

#pragma unroll
    for (int u = 0; u < 8; u++) {
        int v = u * 256 + t;
        int i = v >> 5;
        int c = v & 31;
        int n = nb + i;
        if (n >= NNODES) n = NNODES - 1;
        const unsigned short* srcp = (c < 16) ? h16 : hN16;
        *(short8*)&Xs[i * XPITCH + c * 8] = *(const short8*)&srcp[(size_t)n * DIM + (c & 15) * 8];
    }

    const int wave = t >> 6;
    const int lane = t & 63;
    const int q = lane >> 4;
    const int l16 = lane & 15;

    short8 Bf[2][8];
#pragma unroll
    for (int nn = 0; nn < 2; nn++) {
        int o = (wave * 2 + nn) * 16 + l16;
        const unsigned short* bp = Wl + (size_t)o * TWOD + q * 8;
#pragma unroll
        for (int ks = 0; ks < 8; ks++) Bf[nn][ks] = *(const short8*)(bp + ks * 32);
    }

    __syncthreads();

    floatx4 acc[4][2];
#pragma unroll
    for (int m = 0; m < 4; m++)
#pragma unroll
        for (int nn = 0; nn < 2; nn++) acc[m][nn] = (floatx4)(0.0f);

#pragma unroll
    for (int ks = 0; ks < 8; ks++) {
        short8 Af[4];
        const unsigned short* xb = &Xs[l16 * XPITCH + ks * 32 + q * 8];
#pragma unroll
        for (int m = 0; m < 4; m++) Af[m] = *(const short8*)(xb + m * 16 * XPITCH);
#pragma unroll
        for (int m = 0; m < 4; m++)
#pragma unroll
            for (int nn = 0; nn < 2; nn++)
                acc[m][nn] = __builtin_amdgcn_mfma_f32_16x16x32_bf16(Af[m], Bf[nn][ks], acc[m][nn], 0, 0, 0);
    }

#pragma unroll
    for (int m = 0; m < 4; m++) {
        int ib = m * 16 + q * 4;
#pragma unroll
        for (int nn = 0; nn < 2; nn++) {
            int o = (wave * 2 + nn) * 16 + l16;
            float bl = b_lin[o];
#pragma unroll
            for (int rg = 0; rg < 4; rg++) {
                int n = nb + ib + rg;
                if (n < NNODES) {
                    float val = acc[m][nn][rg] + bl;
                    val = val > 0.0f ? val : SLOPE * val;
                    out[(size_t)n * DIM + o] = val;
                }
            }
        }
    }
}

// ---------------- launcher ----------------
extern "C" void kernel_launch(void* const* d_in, const int* in_sizes, int n_in,
                              void* d_out, int out_size, void* d_ws, size_t ws_size,
                              hipStream_t stream) {
    const float* h     = (const float*)d_in[0];
    const float* rel   = (const float*)d_in[1];
    const float* ratt  = (const float*)d_in[2];
    const float* W_a   = (const float*)d_in[3];
    const float* b_a   = (const float*)d_in[4];
    const float* W_lin = (const float*)d_in[5];
    const float* b_lin = (const float*)d_in[6];
    const int* src = (const int*)d_in[7];
    const int* dst = (const int*)d_in[8];
    const int* ety = (const int*)d_in[9];
    float* out = (float*)d_out;

    // workspace layout (~161 MB)
    float* scoreP = (float*)d_ws;                                   // E
    unsigned short* h16  = (unsigned short*)(scoreP + NEDGES);      // N*128 bf16
    unsigned short* hN16 = h16 + (size_t)NNODES * DIM;              // N*128 bf16
    unsigned short* relT = hN16 + (size_t)NNODES * DIM;             // 8*128*256 bf16
    unsigned short* Wl   = relT + (size_t)NRELS * DIM * TWOD;       // 128*256 bf16
    unsigned short* Wa16 = Wl + (size_t)DIM * TWOD;                 // 64*256 bf16
    uint2* sMeta = (uint2*)(Wa16 + (size_t)ADIM * TWOD);            // SPAD uint2
    int* row_ptr = (int*)(sMeta + SPAD);                            // N+1
    int* histD   = row_ptr + (NNODES + 1);                          // N
    int* cursorD = histD + NNODES;                                  // N
    int* cnts    = cursorD + NNODES;                                // 16
    int* offs    = cnts + 16;                                       // 8
    unsigned short* msgbuf = (unsigned short*)(((uintptr_t)(offs + 8) + 255) & ~(uintptr_t)255); // E*128 bf16

    k_init<<<256, 256, 0, stream>>>(histD, cursorD, cnts);
    k_prep<<<64 + (DIM * TWOD + ADIM * TWOD + 255) / 256, 256, 0, stream>>>(
        rel, W_lin, W_a, relT, Wl, Wa16);
    k_h16<<<(NNODES * DIM / 8 + 255) / 256, 256, 0, stream>>>(h, h16);
    k_hist2<<<(NEDGES + 255) / 256, 256, 0, stream>>>(ety, dst, cnts, histD);
    k_scan<<<1, 1024, 0, stream>>>(histD, row_ptr, cnts, offs, sMeta);
    k_escatter<<<(NEDGES + 255) / 256, 256, 0, stream>>>(
        ety, src, dst, row_ptr, offs, cursorD, cnts + 8, sMeta);
    k_gate_msg<<<(NEDGES + 8 * EPB + EPB - 1) / EPB, 256, 0, stream>>>(
        h16, relT, Wa16, sMeta, b_a, ratt, offs, msgbuf, scoreP);
    k_aggr<<<(NNODES + 3) / 4, 256, 0, stream>>>(msgbuf, scoreP, row_ptr, hN16);
    k_out<<<(NNODES + 63) / 64, 256, 0, stream>>>(h16, hN16, Wl, b_lin, out);
}